// Round 3
// baseline (6859.720 us; speedup 1.0000x reference)
//
#include <hip/hip_runtime.h>
#include <stdint.h>

typedef uint32_t u32;
typedef unsigned long long u64;

#define WGATES 32768
#define BATCH  128
#define LAYERS 32
#define NTYPES 16
#define NC 512                          // compute-role blocks (1 word/thread)
#define WPL (WGATES * 4)                // packed words per layer = 131072
#define F4L (WGATES * BATCH / 4)        // float4 per layer block = 1048576

// ws layout (u32 units): [0,16) tt; [64, 64+33*32) arrive (stride 32);
// [4096, 4096+33*WPL) packed states S_0..S_32.
#define WS_ARRIVE_OFF 64
#define WS_S_OFF      4096
#define WS_NEED_BYTES ((size_t)(WS_S_OFF + 33 * WPL) * 4)

__device__ __forceinline__ u32 lut_eval(u32 tt, u32 a, u32 b, u32 c, u32 d) {
    u32 m[16];
    #pragma unroll
    for (int j = 0; j < 16; ++j)
        m[j] = (u32)(((int)(tt << (31 - j))) >> 31);
    u32 na = ~a, nb = ~b, nc = ~c, nd = ~d;
    u32 v0 = (m[1]&a)|(m[0]&na),  v1 = (m[3]&a)|(m[2]&na);
    u32 v2 = (m[5]&a)|(m[4]&na),  v3 = (m[7]&a)|(m[6]&na);
    u32 v4 = (m[9]&a)|(m[8]&na),  v5 = (m[11]&a)|(m[10]&na);
    u32 v6 = (m[13]&a)|(m[12]&na),v7 = (m[15]&a)|(m[14]&na);
    u32 u0 = (b&v1)|(nb&v0), u1 = (b&v3)|(nb&v2);
    u32 u2 = (b&v5)|(nb&v4), u3 = (b&v7)|(nb&v6);
    u32 w0 = (c&u1)|(nc&u0), w1 = (c&u3)|(nc&u2);
    return (d&w1)|(nd&w0);
}

// ---------------------------------------------------------------------------
// pack_main: tt tables -> ws, zero arrive flags, pack h0 -> S_0.
// ---------------------------------------------------------------------------
__global__ void pack_main(const float* __restrict__ feature,
                          const float* __restrict__ activation,
                          u32* __restrict__ ws) {
    int t = blockIdx.x * 256 + threadIdx.x;
    if (blockIdx.x == 0 && threadIdx.x < NTYPES) {
        u32 tt = 0;
        #pragma unroll
        for (int m = 0; m < 16; ++m)
            tt |= (activation[threadIdx.x * 16 + m] != 0.0f ? 1u : 0u) << m;
        ws[threadIdx.x] = tt;
    }
    if (blockIdx.x == 1) {
        for (int i = threadIdx.x; i < 2048; i += 256)
            ws[WS_ARRIVE_OFF + i] = 0;
    }
    float v = feature[t];
    u64 m = __ballot(v != 0.0f);
    if ((t & 63) == 0)
        ((u64*)(ws + WS_S_OFF))[t >> 6] = m;
}

// ---------------------------------------------------------------------------
// Persistent producer-consumer kernel (cooperative launch for residency).
// Blocks [0,NC): compute chain S_1..S_32 with per-layer flag barriers.
// Blocks [NC,NC+NU): stream-unpack S_0..S_32 to float out, gated per layer.
// ---------------------------------------------------------------------------
__global__ __launch_bounds__(256) void coop_kernel(
        const int* __restrict__ src_idx,
        const int* __restrict__ cell_type,
        u32* __restrict__ ws,
        float* __restrict__ out,
        int NU)
{
    const u32* tt = ws;
    u32* arrive = ws + WS_ARRIVE_OFF;       // arrive[l] at stride 32
    u32* Sb = ws + WS_S_OFF;
    int tid = threadIdx.x;

    if ((int)blockIdx.x < NC) {
        // ---------------- compute role ----------------
        int gid = blockIdx.x * 256 + tid;   // word id in [0, WPL)
        int g = gid >> 2, q = gid & 3;
        for (int l = 1; l <= LAYERS; ++l) {
            if (l > 1) {
                if (tid == 0)
                    while (__hip_atomic_load(arrive + (size_t)(l - 1) * 32,
                                             __ATOMIC_RELAXED,
                                             __HIP_MEMORY_SCOPE_AGENT) < (u32)NC)
                        __builtin_amdgcn_s_sleep(4);
                __syncthreads();
                __threadfence();            // acquire: see other blocks' S_{l-1}
            }
            const u32* Sp = Sb + (size_t)(l - 1) * WPL;
            const int4 s = ((const int4*)(src_idx + (size_t)(l - 1) * WGATES * 4))[g];
            u32 ttv = tt[cell_type[(size_t)(l - 1) * WGATES + g]];
            u32 a = Sp[(u32)s.x * 4 + q];
            u32 b = Sp[(u32)s.y * 4 + q];
            u32 c = Sp[(u32)s.z * 4 + q];
            u32 d = Sp[(u32)s.w * 4 + q];
            (Sb + (size_t)l * WPL)[gid] = lut_eval(ttv, a, b, c, d);
            __threadfence();                // release own store
            __syncthreads();
            if (tid == 0)
                __hip_atomic_fetch_add(arrive + (size_t)l * 32, 1u,
                                       __ATOMIC_RELAXED, __HIP_MEMORY_SCOPE_AGENT);
        }
    } else {
        // ---------------- unpack role ----------------
        int ub = blockIdx.x - NC;
        for (int l = 0; l <= LAYERS; ++l) {
            if (l >= 1) {
                if (tid == 0)
                    while (__hip_atomic_load(arrive + (size_t)l * 32,
                                             __ATOMIC_RELAXED,
                                             __HIP_MEMORY_SCOPE_AGENT) < (u32)NC)
                        __builtin_amdgcn_s_sleep(4);
                __syncthreads();
                __threadfence();            // acquire: see S_l
            }
            const u32* Sl = Sb + (size_t)l * WPL;
            float4* ob = (float4*)(out + (size_t)l * WGATES * BATCH);
            for (u32 i = (u32)ub * 256u + tid; i < (u32)F4L; i += (u32)NU * 256u) {
                u32 wb = Sl[i >> 3];
                u32 sh = (i & 7) * 4;
                float4 f;
                f.x = ((wb >> (sh    )) & 1) ? 1.0f : 0.0f;
                f.y = ((wb >> (sh + 1)) & 1) ? 1.0f : 0.0f;
                f.z = ((wb >> (sh + 2)) & 1) ? 1.0f : 0.0f;
                f.w = ((wb >> (sh + 3)) & 1) ? 1.0f : 0.0f;
                ob[i] = f;
            }
        }
    }
}

// ======================= R2 fallback path (proven) =========================
__global__ void pack_kernel_fb(const float* __restrict__ feature,
                               const float* __restrict__ activation,
                               float* __restrict__ out,
                               u32* __restrict__ tt_ws,
                               u32* __restrict__ buf0) {
    int t = blockIdx.x * 256 + threadIdx.x;
    if (blockIdx.x == 0 && threadIdx.x < NTYPES) {
        u32 tt = 0;
        #pragma unroll
        for (int m = 0; m < 16; ++m)
            tt |= (activation[threadIdx.x * 16 + m] != 0.0f ? 1u : 0u) << m;
        tt_ws[threadIdx.x] = tt;
    }
    float v = feature[t];
    out[t] = v;
    u64 m = __ballot(v != 0.0f);
    if ((t & 63) == 0)
        ((u64*)buf0)[t >> 6] = m;
}

__global__ void fused_kernel_fb(const u32* __restrict__ prev,
                                u32* __restrict__ next,
                                const int* __restrict__ src_idx,
                                const int* __restrict__ cell_type,
                                const u32* __restrict__ tt_ws,
                                const u32* __restrict__ upacked,
                                float* __restrict__ uout,
                                int do_compute)
{
    int tid = threadIdx.x;
    if (do_compute && blockIdx.x < 512) {
        int gl = tid >> 2, q = tid & 3;
        int wg = blockIdx.x * 64 + gl;
        const int4 s = ((const int4*)src_idx)[wg];
        u32 tt = tt_ws[cell_type[wg]];
        u32 a = prev[(size_t)s.x * 4 + q];
        u32 b = prev[(size_t)s.y * 4 + q];
        u32 c = prev[(size_t)s.z * 4 + q];
        u32 d = prev[(size_t)s.w * 4 + q];
        next[(size_t)wg * 4 + q] = lut_eval(tt, a, b, c, d);
        return;
    }
    if (uout == nullptr) return;
    int ub = do_compute ? (int)blockIdx.x - 512 : (int)blockIdx.x;
    #pragma unroll
    for (int r = 0; r < 2; ++r) {
        int fi = ((ub * 2 + r) * 256 + tid) * 4;
        u32 wb = upacked[fi >> 5];
        int sh = fi & 31;
        float4 f;
        f.x = ((wb >> (sh    )) & 1) ? 1.0f : 0.0f;
        f.y = ((wb >> (sh + 1)) & 1) ? 1.0f : 0.0f;
        f.z = ((wb >> (sh + 2)) & 1) ? 1.0f : 0.0f;
        f.w = ((wb >> (sh + 3)) & 1) ? 1.0f : 0.0f;
        ((float4*)uout)[fi >> 2] = f;
    }
}

static void launch_fallback(const float* feature, const float* activation,
                            const int* src_idx, const int* cell_type,
                            float* out, void* d_ws, hipStream_t stream) {
    u32* tt_ws = (u32*)d_ws;
    u32* bufA = (u32*)((char*)d_ws + 1024);
    u32* bufB = (u32*)((char*)d_ws + 1024 + WGATES * 16);
    pack_kernel_fb<<<WGATES * BATCH / 256, 256, 0, stream>>>(
        feature, activation, out, tt_ws, bufA);
    for (int l = 1; l <= LAYERS; ++l) {
        u32* prev = ((l - 1) & 1) ? bufB : bufA;
        u32* next = ((l - 1) & 1) ? bufA : bufB;
        float* uout = (l >= 2) ? out + (size_t)(l - 1) * WGATES * BATCH : nullptr;
        fused_kernel_fb<<<512 + 2048, 256, 0, stream>>>(
            prev, next,
            src_idx + (size_t)(l - 1) * WGATES * 4,
            cell_type + (size_t)(l - 1) * WGATES,
            tt_ws, prev, uout, 1);
    }
    u32* s32 = ((LAYERS - 1) & 1) ? bufA : bufB;
    fused_kernel_fb<<<2048, 256, 0, stream>>>(
        s32, s32, src_idx, cell_type, tt_ws,
        s32, out + (size_t)LAYERS * WGATES * BATCH, 0);
}

extern "C" void kernel_launch(void* const* d_in, const int* in_sizes, int n_in,
                              void* d_out, int out_size, void* d_ws, size_t ws_size,
                              hipStream_t stream) {
    const float* feature    = (const float*)d_in[0];
    const float* activation = (const float*)d_in[1];
    const int*   src_idx    = (const int*)d_in[2];
    const int*   cell_type  = (const int*)d_in[3];
    float* out = (float*)d_out;

    bool coop_ok = (ws_size >= WS_NEED_BYTES);
    int G = 0, NU = 0;
    if (coop_ok) {
        int dev = 0;
        hipGetDevice(&dev);
        int numCU = 0, bpc = 0;
        if (hipDeviceGetAttribute(&numCU, hipDeviceAttributeMultiprocessorCount, dev)
                != hipSuccess) coop_ok = false;
        if (coop_ok &&
            hipOccupancyMaxActiveBlocksPerMultiprocessor(
                &bpc, (const void*)coop_kernel, 256, 0) != hipSuccess) coop_ok = false;
        if (coop_ok) {
            G = bpc * numCU;
            if (G > 2048) G = 2048;
            NU = G - NC;
            if (NU < 256) coop_ok = false;
        }
    }

    if (coop_ok) {
        u32* ws = (u32*)d_ws;
        pack_main<<<WGATES * BATCH / 256, 256, 0, stream>>>(feature, activation, ws);
        void* args[] = {(void*)&src_idx, (void*)&cell_type, (void*)&ws,
                        (void*)&out, (void*)&NU};
        hipError_t e = hipLaunchCooperativeKernel(
            (const void*)coop_kernel, dim3(G), dim3(256), args, 0, stream);
        if (e == hipSuccess) return;
        // cooperative launch rejected (e.g. under capture) -> fall through
    }
    launch_fallback(feature, activation, src_idx, cell_type, out, d_ws, stream);
}

// Round 5
// 1337.652 us; speedup vs baseline: 5.1282x; 5.1282x over previous
//
#include <hip/hip_runtime.h>
#include <stdint.h>

typedef uint32_t u32;
typedef unsigned long long u64;
typedef float f4 __attribute__((ext_vector_type(4)));

#define WGATES 32768
#define BATCH  128
#define LAYERS 32
#define NTYPES 16
#define NC 512                          // compute-role blocks (1 word/thread)
#define WPL (WGATES * 4)                // packed words per layer = 131072
#define F4L (WGATES * BATCH / 4)        // float4 per layer block = 1048576

// ws layout (u32 units): [0,16) tt; [64, 64+33*32) arrive (stride 32);
// [4096, 4096+33*WPL) packed states S_0..S_32.
#define WS_ARRIVE_OFF 64
#define WS_S_OFF      4096
#define WS_NEED_BYTES ((size_t)(WS_S_OFF + 33 * WPL) * 4)

// Device-coherent (agent-scope, sc1) accesses: per-access coherence across
// XCDs with NO cache flushes (the R3 mistake was __threadfence -> buffer_wbl2).
__device__ __forceinline__ u32 agent_load(const u32* p) {
    return __hip_atomic_load(p, __ATOMIC_RELAXED, __HIP_MEMORY_SCOPE_AGENT);
}
__device__ __forceinline__ void agent_store(u32* p, u32 v) {
    __hip_atomic_store(p, v, __ATOMIC_RELAXED, __HIP_MEMORY_SCOPE_AGENT);
}

__device__ __forceinline__ u32 lut_eval(u32 tt, u32 a, u32 b, u32 c, u32 d) {
    u32 m[16];
    #pragma unroll
    for (int j = 0; j < 16; ++j)
        m[j] = (u32)(((int)(tt << (31 - j))) >> 31);
    u32 na = ~a, nb = ~b, nc = ~c, nd = ~d;
    u32 v0 = (m[1]&a)|(m[0]&na),  v1 = (m[3]&a)|(m[2]&na);
    u32 v2 = (m[5]&a)|(m[4]&na),  v3 = (m[7]&a)|(m[6]&na);
    u32 v4 = (m[9]&a)|(m[8]&na),  v5 = (m[11]&a)|(m[10]&na);
    u32 v6 = (m[13]&a)|(m[12]&na),v7 = (m[15]&a)|(m[14]&na);
    u32 u0 = (b&v1)|(nb&v0), u1 = (b&v3)|(nb&v2);
    u32 u2 = (b&v5)|(nb&v4), u3 = (b&v7)|(nb&v6);
    u32 w0 = (c&u1)|(nc&u0), w1 = (c&u3)|(nc&u2);
    return (d&w1)|(nd&w0);
}

// ---------------------------------------------------------------------------
// pack_main: tt tables -> ws, zero arrive flags, pack h0 -> S_0.
// ---------------------------------------------------------------------------
__global__ void pack_main(const float* __restrict__ feature,
                          const float* __restrict__ activation,
                          u32* __restrict__ ws) {
    int t = blockIdx.x * 256 + threadIdx.x;
    if (blockIdx.x == 0 && threadIdx.x < NTYPES) {
        u32 tt = 0;
        #pragma unroll
        for (int m = 0; m < 16; ++m)
            tt |= (activation[threadIdx.x * 16 + m] != 0.0f ? 1u : 0u) << m;
        ws[threadIdx.x] = tt;
    }
    if (blockIdx.x == 1) {
        for (int i = threadIdx.x; i < 2048; i += 256)
            ws[WS_ARRIVE_OFF + i] = 0;
    }
    float v = feature[t];
    u64 m = __ballot(v != 0.0f);
    if ((t & 63) == 0)
        ((u64*)(ws + WS_S_OFF))[t >> 6] = m;
}

// ---------------------------------------------------------------------------
// Persistent producer-consumer kernel (cooperative launch for residency).
// Blocks [0,NC): compute chain S_1..S_32 with per-layer flag barriers.
// Blocks [NC,NC+NU): stream-unpack S_0..S_32 to float out, gated per layer.
// All shared state goes through agent-scope (sc1) accesses; ordering is
// per-wave s_waitcnt vmcnt(0) + __syncthreads + one relaxed agent add.
// ---------------------------------------------------------------------------
__global__ __launch_bounds__(256) void coop_kernel(
        const int* __restrict__ src_idx,
        const int* __restrict__ cell_type,
        u32* __restrict__ ws,
        float* __restrict__ out,
        int NU)
{
    const u32* tt = ws;
    u32* arrive = ws + WS_ARRIVE_OFF;       // arrive[l] at word-stride 32
    u32* Sb = ws + WS_S_OFF;
    int tid = threadIdx.x;

    if ((int)blockIdx.x < NC) {
        // ---------------- compute role ----------------
        int gid = blockIdx.x * 256 + tid;   // word id in [0, WPL)
        int g = gid >> 2, q = gid & 3;
        for (int l = 1; l <= LAYERS; ++l) {
            if (l > 1) {
                if (tid == 0)
                    while (agent_load(arrive + (size_t)(l - 1) * 32) < (u32)NC)
                        __builtin_amdgcn_s_sleep(2);
                __syncthreads();
                asm volatile("" ::: "memory");
            }
            const u32* Sp = Sb + (size_t)(l - 1) * WPL;
            const int4 s = ((const int4*)(src_idx + (size_t)(l - 1) * WGATES * 4))[g];
            u32 ttv = tt[cell_type[(size_t)(l - 1) * WGATES + g]];
            u32 a = agent_load(Sp + (u32)s.x * 4 + q);
            u32 b = agent_load(Sp + (u32)s.y * 4 + q);
            u32 c = agent_load(Sp + (u32)s.z * 4 + q);
            u32 d = agent_load(Sp + (u32)s.w * 4 + q);
            agent_store(Sb + (size_t)l * WPL + gid, lut_eval(ttv, a, b, c, d));
            // Release: sc1 store is globally visible once vmcnt retires it.
            asm volatile("s_waitcnt vmcnt(0)" ::: "memory");
            __syncthreads();
            if (tid == 0)
                __hip_atomic_fetch_add(arrive + (size_t)l * 32, 1u,
                                       __ATOMIC_RELAXED, __HIP_MEMORY_SCOPE_AGENT);
        }
    } else {
        // ---------------- unpack role ----------------
        int ub = blockIdx.x - NC;
        for (int l = 0; l <= LAYERS; ++l) {
            if (l >= 1) {
                if (tid == 0)
                    while (agent_load(arrive + (size_t)l * 32) < (u32)NC)
                        __builtin_amdgcn_s_sleep(2);
                __syncthreads();
                asm volatile("" ::: "memory");
            }
            const u32* Sl = Sb + (size_t)l * WPL;
            f4* ob = (f4*)(out + (size_t)l * WGATES * BATCH);
            for (u32 i = (u32)ub * 256u + tid; i < (u32)F4L; i += (u32)NU * 256u) {
                u32 wb = agent_load(Sl + (i >> 3));
                u32 sh = (i & 7) * 4;
                f4 f;
                f.x = ((wb >> (sh    )) & 1) ? 1.0f : 0.0f;
                f.y = ((wb >> (sh + 1)) & 1) ? 1.0f : 0.0f;
                f.z = ((wb >> (sh + 2)) & 1) ? 1.0f : 0.0f;
                f.w = ((wb >> (sh + 3)) & 1) ? 1.0f : 0.0f;
                __builtin_nontemporal_store(f, ob + i);   // out never re-read
            }
        }
    }
}

// ======================= R2 fallback path (proven) =========================
__global__ void pack_kernel_fb(const float* __restrict__ feature,
                               const float* __restrict__ activation,
                               float* __restrict__ out,
                               u32* __restrict__ tt_ws,
                               u32* __restrict__ buf0) {
    int t = blockIdx.x * 256 + threadIdx.x;
    if (blockIdx.x == 0 && threadIdx.x < NTYPES) {
        u32 tt = 0;
        #pragma unroll
        for (int m = 0; m < 16; ++m)
            tt |= (activation[threadIdx.x * 16 + m] != 0.0f ? 1u : 0u) << m;
        tt_ws[threadIdx.x] = tt;
    }
    float v = feature[t];
    out[t] = v;
    u64 m = __ballot(v != 0.0f);
    if ((t & 63) == 0)
        ((u64*)buf0)[t >> 6] = m;
}

__global__ void fused_kernel_fb(const u32* __restrict__ prev,
                                u32* __restrict__ next,
                                const int* __restrict__ src_idx,
                                const int* __restrict__ cell_type,
                                const u32* __restrict__ tt_ws,
                                const u32* __restrict__ upacked,
                                float* __restrict__ uout,
                                int do_compute)
{
    int tid = threadIdx.x;
    if (do_compute && blockIdx.x < 512) {
        int gl = tid >> 2, q = tid & 3;
        int wg = blockIdx.x * 64 + gl;
        const int4 s = ((const int4*)src_idx)[wg];
        u32 tt = tt_ws[cell_type[wg]];
        u32 a = prev[(size_t)s.x * 4 + q];
        u32 b = prev[(size_t)s.y * 4 + q];
        u32 c = prev[(size_t)s.z * 4 + q];
        u32 d = prev[(size_t)s.w * 4 + q];
        next[(size_t)wg * 4 + q] = lut_eval(tt, a, b, c, d);
        return;
    }
    if (uout == nullptr) return;
    int ub = do_compute ? (int)blockIdx.x - 512 : (int)blockIdx.x;
    #pragma unroll
    for (int r = 0; r < 2; ++r) {
        int fi = ((ub * 2 + r) * 256 + tid) * 4;
        u32 wb = upacked[fi >> 5];
        int sh = fi & 31;
        f4 f;
        f.x = ((wb >> (sh    )) & 1) ? 1.0f : 0.0f;
        f.y = ((wb >> (sh + 1)) & 1) ? 1.0f : 0.0f;
        f.z = ((wb >> (sh + 2)) & 1) ? 1.0f : 0.0f;
        f.w = ((wb >> (sh + 3)) & 1) ? 1.0f : 0.0f;
        ((f4*)uout)[fi >> 2] = f;
    }
}

static void launch_fallback(const float* feature, const float* activation,
                            const int* src_idx, const int* cell_type,
                            float* out, void* d_ws, hipStream_t stream) {
    u32* tt_ws = (u32*)d_ws;
    u32* bufA = (u32*)((char*)d_ws + 1024);
    u32* bufB = (u32*)((char*)d_ws + 1024 + WGATES * 16);
    pack_kernel_fb<<<WGATES * BATCH / 256, 256, 0, stream>>>(
        feature, activation, out, tt_ws, bufA);
    for (int l = 1; l <= LAYERS; ++l) {
        u32* prev = ((l - 1) & 1) ? bufB : bufA;
        u32* next = ((l - 1) & 1) ? bufA : bufB;
        float* uout = (l >= 2) ? out + (size_t)(l - 1) * WGATES * BATCH : nullptr;
        fused_kernel_fb<<<512 + 2048, 256, 0, stream>>>(
            prev, next,
            src_idx + (size_t)(l - 1) * WGATES * 4,
            cell_type + (size_t)(l - 1) * WGATES,
            tt_ws, prev, uout, 1);
    }
    u32* s32 = ((LAYERS - 1) & 1) ? bufA : bufB;
    fused_kernel_fb<<<2048, 256, 0, stream>>>(
        s32, s32, src_idx, cell_type, tt_ws,
        s32, out + (size_t)LAYERS * WGATES * BATCH, 0);
}

extern "C" void kernel_launch(void* const* d_in, const int* in_sizes, int n_in,
                              void* d_out, int out_size, void* d_ws, size_t ws_size,
                              hipStream_t stream) {
    const float* feature    = (const float*)d_in[0];
    const float* activation = (const float*)d_in[1];
    const int*   src_idx    = (const int*)d_in[2];
    const int*   cell_type  = (const int*)d_in[3];
    float* out = (float*)d_out;

    bool coop_ok = (ws_size >= WS_NEED_BYTES);
    int G = 0, NU = 0;
    if (coop_ok) {
        int dev = 0;
        (void)hipGetDevice(&dev);
        int numCU = 0, bpc = 0;
        if (hipDeviceGetAttribute(&numCU, hipDeviceAttributeMultiprocessorCount, dev)
                != hipSuccess) coop_ok = false;
        if (coop_ok &&
            hipOccupancyMaxActiveBlocksPerMultiprocessor(
                &bpc, (const void*)coop_kernel, 256, 0) != hipSuccess) coop_ok = false;
        if (coop_ok) {
            G = bpc * numCU;
            if (G > 2048) G = 2048;
            NU = G - NC;
            if (NU < 256) coop_ok = false;
        }
    }

    if (coop_ok) {
        u32* ws = (u32*)d_ws;
        pack_main<<<WGATES * BATCH / 256, 256, 0, stream>>>(feature, activation, ws);
        void* args[] = {(void*)&src_idx, (void*)&cell_type, (void*)&ws,
                        (void*)&out, (void*)&NU};
        hipError_t e = hipLaunchCooperativeKernel(
            (const void*)coop_kernel, dim3(G), dim3(256), args, 0, stream);
        if (e == hipSuccess) return;
        // cooperative launch rejected (e.g. under capture) -> fall through
    }
    launch_fallback(feature, activation, src_idx, cell_type, out, d_ws, stream);
}

// Round 6
// 259.103 us; speedup vs baseline: 26.4749x; 5.1626x over previous
//
#include <hip/hip_runtime.h>
#include <stdint.h>

typedef uint32_t u32;
typedef unsigned long long u64;
typedef float f4 __attribute__((ext_vector_type(4)));

#define WGATES 32768
#define BATCH  128
#define LAYERS 32
#define NTYPES 16
#define NC 512                          // compute-role blocks (1 word/thread)
#define WPL (WGATES * 4)                // packed words per layer = 131072
#define F4L (WGATES * BATCH / 4)        // float4 per layer block = 1048576

// ws layout (u32 units):
//   [0,16)                      tt truth tables
//   [1024, 1024+33*1024)        arrive counters: layer l at +l*1024, 64
//                               sub-counters 64B apart (j*16)
//   [34816, 34816+33*WPL)       packed states S_0..S_32 (each written once)
#define WS_ARRIVE_OFF 1024
#define WS_S_OFF      34816
#define WS_NEED_BYTES ((size_t)(WS_S_OFF + 33 * WPL) * 4)

// Agent-scope (sc1) accesses: ONLY for sync flags. Data uses normal cached
// loads (safe: each S_l address is written once, and never cached by a
// consumer XCD before the producer's sc1 store reaches the coherence point;
// kernel-start acquire invalidated any stale lines).
__device__ __forceinline__ u32 agent_load(const u32* p) {
    return __hip_atomic_load(p, __ATOMIC_RELAXED, __HIP_MEMORY_SCOPE_AGENT);
}
__device__ __forceinline__ void agent_store(u32* p, u32 v) {
    __hip_atomic_store(p, v, __ATOMIC_RELAXED, __HIP_MEMORY_SCOPE_AGENT);
}

__device__ __forceinline__ u32 lut_eval(u32 tt, u32 a, u32 b, u32 c, u32 d) {
    u32 m[16];
    #pragma unroll
    for (int j = 0; j < 16; ++j)
        m[j] = (u32)(((int)(tt << (31 - j))) >> 31);
    u32 na = ~a, nb = ~b, nc = ~c, nd = ~d;
    u32 v0 = (m[1]&a)|(m[0]&na),  v1 = (m[3]&a)|(m[2]&na);
    u32 v2 = (m[5]&a)|(m[4]&na),  v3 = (m[7]&a)|(m[6]&na);
    u32 v4 = (m[9]&a)|(m[8]&na),  v5 = (m[11]&a)|(m[10]&na);
    u32 v6 = (m[13]&a)|(m[12]&na),v7 = (m[15]&a)|(m[14]&na);
    u32 u0 = (b&v1)|(nb&v0), u1 = (b&v3)|(nb&v2);
    u32 u2 = (b&v5)|(nb&v4), u3 = (b&v7)|(nb&v6);
    u32 w0 = (c&u1)|(nc&u0), w1 = (c&u3)|(nc&u2);
    return (d&w1)|(nd&w0);
}

// Wave0 polls the 64 sub-counters of layer l (lane i -> counter i); the
// divergent loop exits only when every lane sees its counter complete.
__device__ __forceinline__ void wait_layer(const u32* arrive, int l, int tid) {
    if (tid < 64) {
        const u32* p = arrive + (size_t)l * 1024 + tid * 16;
        while (agent_load(p) < (u32)(NC / 64))
            __builtin_amdgcn_s_sleep(8);
    }
    __syncthreads();
    asm volatile("" ::: "memory");   // no data load hoisted above this point
}

// ---------------------------------------------------------------------------
// pack_main: tt tables -> ws, zero arrive counters, pack h0 -> S_0.
// ---------------------------------------------------------------------------
__global__ void pack_main(const float* __restrict__ feature,
                          const float* __restrict__ activation,
                          u32* __restrict__ ws) {
    int t = blockIdx.x * 256 + threadIdx.x;
    if (blockIdx.x == 0 && threadIdx.x < NTYPES) {
        u32 tt = 0;
        #pragma unroll
        for (int m = 0; m < 16; ++m)
            tt |= (activation[threadIdx.x * 16 + m] != 0.0f ? 1u : 0u) << m;
        ws[threadIdx.x] = tt;
    }
    int z = (int)blockIdx.x - 1;
    if (z >= 0 && z < 33 * 4)          // 132 blocks x 256 = 33792 words
        ws[WS_ARRIVE_OFF + z * 256 + threadIdx.x] = 0;
    float v = feature[t];
    u64 m = __ballot(v != 0.0f);
    if ((t & 63) == 0)
        ((u64*)(ws + WS_S_OFF))[t >> 6] = m;
}

// ---------------------------------------------------------------------------
// Persistent producer-consumer kernel (cooperative launch for residency).
// Blocks [0,NC): compute chain S_1..S_32, fan-in arrive counters.
// Blocks [NC,NC+NU): stream-unpack S_0..S_32 to float out, gated per layer.
// ---------------------------------------------------------------------------
__global__ __launch_bounds__(256) void coop_kernel(
        const int* __restrict__ src_idx,
        const int* __restrict__ cell_type,
        u32* __restrict__ ws,
        float* __restrict__ out,
        int NU)
{
    u32* arrive = ws + WS_ARRIVE_OFF;
    u32* Sb = ws + WS_S_OFF;
    int tid = threadIdx.x;
    __shared__ u32 stt[NTYPES];
    if (tid < NTYPES) stt[tid] = ws[tid];
    __syncthreads();

    if ((int)blockIdx.x < NC) {
        // ---------------- compute role ----------------
        int gid = blockIdx.x * 256 + tid;   // word id in [0, WPL)
        int g = gid >> 2, q = gid & 3;
        int sub = blockIdx.x & 63;
        for (int l = 1; l <= LAYERS; ++l) {
            // Issue index loads BEFORE the flag wait (HBM latency hides there).
            const int4 s = ((const int4*)(src_idx + (size_t)(l - 1) * WGATES * 4))[g];
            u32 ttv = stt[cell_type[(size_t)(l - 1) * WGATES + g]];
            if (l > 1) wait_layer(arrive, l - 1, tid);
            const u32* Sp = Sb + (size_t)(l - 1) * WPL;
            u32 a = Sp[(u32)s.x * 4 + q];      // normal cached loads
            u32 b = Sp[(u32)s.y * 4 + q];
            u32 c = Sp[(u32)s.z * 4 + q];
            u32 d = Sp[(u32)s.w * 4 + q];
            agent_store(Sb + (size_t)l * WPL + gid, lut_eval(ttv, a, b, c, d));
            asm volatile("s_waitcnt vmcnt(0)" ::: "memory");  // store acked
            __syncthreads();
            if (tid == 0)
                __hip_atomic_fetch_add(arrive + (size_t)l * 1024 + sub * 16, 1u,
                                       __ATOMIC_RELAXED, __HIP_MEMORY_SCOPE_AGENT);
        }
    } else {
        // ---------------- unpack role ----------------
        int ub = blockIdx.x - NC;
        for (int l = 0; l <= LAYERS; ++l) {
            if (l >= 1) wait_layer(arrive, l, tid);
            const u32* Sl = Sb + (size_t)l * WPL;
            f4* ob = (f4*)(out + (size_t)l * WGATES * BATCH);
            for (u32 i = (u32)ub * 256u + tid; i < (u32)F4L; i += (u32)NU * 256u) {
                u32 wb = Sl[i >> 3];               // cached (L2-resident)
                u32 sh = (i & 7) * 4;
                f4 f;
                f.x = ((wb >> (sh    )) & 1) ? 1.0f : 0.0f;
                f.y = ((wb >> (sh + 1)) & 1) ? 1.0f : 0.0f;
                f.z = ((wb >> (sh + 2)) & 1) ? 1.0f : 0.0f;
                f.w = ((wb >> (sh + 3)) & 1) ? 1.0f : 0.0f;
                __builtin_nontemporal_store(f, ob + i);   // out never re-read
            }
        }
    }
}

// ======================= R2 fallback path (proven) =========================
__global__ void pack_kernel_fb(const float* __restrict__ feature,
                               const float* __restrict__ activation,
                               float* __restrict__ out,
                               u32* __restrict__ tt_ws,
                               u32* __restrict__ buf0) {
    int t = blockIdx.x * 256 + threadIdx.x;
    if (blockIdx.x == 0 && threadIdx.x < NTYPES) {
        u32 tt = 0;
        #pragma unroll
        for (int m = 0; m < 16; ++m)
            tt |= (activation[threadIdx.x * 16 + m] != 0.0f ? 1u : 0u) << m;
        tt_ws[threadIdx.x] = tt;
    }
    float v = feature[t];
    out[t] = v;
    u64 m = __ballot(v != 0.0f);
    if ((t & 63) == 0)
        ((u64*)buf0)[t >> 6] = m;
}

__global__ void fused_kernel_fb(const u32* __restrict__ prev,
                                u32* __restrict__ next,
                                const int* __restrict__ src_idx,
                                const int* __restrict__ cell_type,
                                const u32* __restrict__ tt_ws,
                                const u32* __restrict__ upacked,
                                float* __restrict__ uout,
                                int do_compute)
{
    int tid = threadIdx.x;
    if (do_compute && blockIdx.x < 512) {
        int gl = tid >> 2, q = tid & 3;
        int wg = blockIdx.x * 64 + gl;
        const int4 s = ((const int4*)src_idx)[wg];
        u32 tt = tt_ws[cell_type[wg]];
        u32 a = prev[(size_t)s.x * 4 + q];
        u32 b = prev[(size_t)s.y * 4 + q];
        u32 c = prev[(size_t)s.z * 4 + q];
        u32 d = prev[(size_t)s.w * 4 + q];
        next[(size_t)wg * 4 + q] = lut_eval(tt, a, b, c, d);
        return;
    }
    if (uout == nullptr) return;
    int ub = do_compute ? (int)blockIdx.x - 512 : (int)blockIdx.x;
    #pragma unroll
    for (int r = 0; r < 2; ++r) {
        int fi = ((ub * 2 + r) * 256 + tid) * 4;
        u32 wb = upacked[fi >> 5];
        int sh = fi & 31;
        f4 f;
        f.x = ((wb >> (sh    )) & 1) ? 1.0f : 0.0f;
        f.y = ((wb >> (sh + 1)) & 1) ? 1.0f : 0.0f;
        f.z = ((wb >> (sh + 2)) & 1) ? 1.0f : 0.0f;
        f.w = ((wb >> (sh + 3)) & 1) ? 1.0f : 0.0f;
        ((f4*)uout)[fi >> 2] = f;
    }
}

static void launch_fallback(const float* feature, const float* activation,
                            const int* src_idx, const int* cell_type,
                            float* out, void* d_ws, hipStream_t stream) {
    u32* tt_ws = (u32*)d_ws;
    u32* bufA = (u32*)((char*)d_ws + 1024);
    u32* bufB = (u32*)((char*)d_ws + 1024 + WGATES * 16);
    pack_kernel_fb<<<WGATES * BATCH / 256, 256, 0, stream>>>(
        feature, activation, out, tt_ws, bufA);
    for (int l = 1; l <= LAYERS; ++l) {
        u32* prev = ((l - 1) & 1) ? bufB : bufA;
        u32* next = ((l - 1) & 1) ? bufA : bufB;
        float* uout = (l >= 2) ? out + (size_t)(l - 1) * WGATES * BATCH : nullptr;
        fused_kernel_fb<<<512 + 2048, 256, 0, stream>>>(
            prev, next,
            src_idx + (size_t)(l - 1) * WGATES * 4,
            cell_type + (size_t)(l - 1) * WGATES,
            tt_ws, prev, uout, 1);
    }
    u32* s32 = ((LAYERS - 1) & 1) ? bufA : bufB;
    fused_kernel_fb<<<2048, 256, 0, stream>>>(
        s32, s32, src_idx, cell_type, tt_ws,
        s32, out + (size_t)LAYERS * WGATES * BATCH, 0);
}

extern "C" void kernel_launch(void* const* d_in, const int* in_sizes, int n_in,
                              void* d_out, int out_size, void* d_ws, size_t ws_size,
                              hipStream_t stream) {
    const float* feature    = (const float*)d_in[0];
    const float* activation = (const float*)d_in[1];
    const int*   src_idx    = (const int*)d_in[2];
    const int*   cell_type  = (const int*)d_in[3];
    float* out = (float*)d_out;

    bool coop_ok = (ws_size >= WS_NEED_BYTES);
    int G = 0, NU = 0;
    if (coop_ok) {
        int dev = 0;
        (void)hipGetDevice(&dev);
        int numCU = 0, bpc = 0;
        if (hipDeviceGetAttribute(&numCU, hipDeviceAttributeMultiprocessorCount, dev)
                != hipSuccess) coop_ok = false;
        if (coop_ok &&
            hipOccupancyMaxActiveBlocksPerMultiprocessor(
                &bpc, (const void*)coop_kernel, 256, 0) != hipSuccess) coop_ok = false;
        if (coop_ok) {
            G = bpc * numCU;
            if (G > 2048) G = 2048;
            NU = G - NC;
            if (NU < 256) coop_ok = false;
        }
    }

    if (coop_ok) {
        u32* ws = (u32*)d_ws;
        pack_main<<<WGATES * BATCH / 256, 256, 0, stream>>>(feature, activation, ws);
        void* args[] = {(void*)&src_idx, (void*)&cell_type, (void*)&ws,
                        (void*)&out, (void*)&NU};
        hipError_t e = hipLaunchCooperativeKernel(
            (const void*)coop_kernel, dim3(G), dim3(256), args, 0, stream);
        if (e == hipSuccess) return;
        // cooperative launch rejected -> fall through
    }
    launch_fallback(feature, activation, src_idx, cell_type, out, d_ws, stream);
}

// Round 7
// 168.236 us; speedup vs baseline: 40.7744x; 1.5401x over previous
//
#include <hip/hip_runtime.h>
#include <stdint.h>

typedef uint32_t u32;
typedef unsigned long long u64;
typedef float f4 __attribute__((ext_vector_type(4)));

#define WGATES 32768
#define BATCH  128
#define LAYERS 32
#define NTYPES 16
#define NC 512                          // compute-role blocks (1 word/thread)
#define WPL (WGATES * 4)                // packed words per layer = 131072
#define F4L (WGATES * BATCH / 4)        // float4 per layer block = 1048576

// ws layout (u32 units):
//   [0,16)              tt truth tables
//   [1024, 34816)       sub-counters: layer l at 1024+l*1024, j=0..63 at +j*16
//   [34816, 35344)      lvl2 counters: layer l at 34816+l*16
//   [35840, 69632)      done flags: layer l at 35840+l*1024, j=0..63 at +j*16
//   [69632, +33*WPL)    packed states S_0..S_32 (each address written once)
#define WS_SUB_OFF    1024
#define WS_LVL2_OFF   34816
#define WS_DONE_OFF   35840
#define WS_S_OFF      69632
#define WS_NEED_BYTES ((size_t)(WS_S_OFF + 33 * WPL) * 4)

// Agent-scope (sc1) accesses: ONLY for sync. Data uses normal cached loads
// (each S_l address is written once; consumers first-touch it only after the
// producer's sc1 store reached the coherence point).
__device__ __forceinline__ u32 agent_load(const u32* p) {
    return __hip_atomic_load(p, __ATOMIC_RELAXED, __HIP_MEMORY_SCOPE_AGENT);
}
__device__ __forceinline__ void agent_store(u32* p, u32 v) {
    __hip_atomic_store(p, v, __ATOMIC_RELAXED, __HIP_MEMORY_SCOPE_AGENT);
}
__device__ __forceinline__ u32 agent_add(u32* p, u32 v) {
    return __hip_atomic_fetch_add(p, v, __ATOMIC_RELAXED, __HIP_MEMORY_SCOPE_AGENT);
}

__device__ __forceinline__ u32 lut_eval(u32 tt, u32 a, u32 b, u32 c, u32 d) {
    u32 m[16];
    #pragma unroll
    for (int j = 0; j < 16; ++j)
        m[j] = (u32)(((int)(tt << (31 - j))) >> 31);
    u32 na = ~a, nb = ~b, nc = ~c, nd = ~d;
    u32 v0 = (m[1]&a)|(m[0]&na),  v1 = (m[3]&a)|(m[2]&na);
    u32 v2 = (m[5]&a)|(m[4]&na),  v3 = (m[7]&a)|(m[6]&na);
    u32 v4 = (m[9]&a)|(m[8]&na),  v5 = (m[11]&a)|(m[10]&na);
    u32 v6 = (m[13]&a)|(m[12]&na),v7 = (m[15]&a)|(m[14]&na);
    u32 u0 = (b&v1)|(nb&v0), u1 = (b&v3)|(nb&v2);
    u32 u2 = (b&v5)|(nb&v4), u3 = (b&v7)|(nb&v6);
    u32 w0 = (c&u1)|(nc&u0), w1 = (c&u3)|(nc&u2);
    return (d&w1)|(nd&w0);
}

// Single-lane, single-line poll: total sc1 poll traffic ~1 read/block/0.1us
// spread over 64 lines -> negligible at the coherence point.
__device__ __forceinline__ void wait_done(const u32* ws, int l, int line, int tid) {
    if (tid == 0) {
        const u32* p = ws + WS_DONE_OFF + (size_t)l * 1024 + line * 16;
        while (agent_load(p) == 0)
            __builtin_amdgcn_s_sleep(4);
    }
    __syncthreads();
    asm volatile("" ::: "memory");   // nothing hoisted above the gate
}

// ---------------------------------------------------------------------------
// pack_main: tt tables -> ws, zero all sync state, pack h0 -> S_0.
// ---------------------------------------------------------------------------
__global__ void pack_main(const float* __restrict__ feature,
                          const float* __restrict__ activation,
                          u32* __restrict__ ws) {
    int t = blockIdx.x * 256 + threadIdx.x;
    if (blockIdx.x == 0 && threadIdx.x < NTYPES) {
        u32 tt = 0;
        #pragma unroll
        for (int m = 0; m < 16; ++m)
            tt |= (activation[threadIdx.x * 16 + m] != 0.0f ? 1u : 0u) << m;
        ws[threadIdx.x] = tt;
    }
    int z = (int)blockIdx.x - 1;
    if (z >= 0 && z < 268)             // zero [1024, 69632): sub+lvl2+done
        ws[1024 + z * 256 + threadIdx.x] = 0;
    float v = feature[t];
    u64 m = __ballot(v != 0.0f);
    if ((t & 63) == 0)
        ((u64*)(ws + WS_S_OFF))[t >> 6] = m;
}

// ---------------------------------------------------------------------------
// Persistent producer-consumer kernel (cooperative launch for residency).
// Blocks [0,NC): compute chain S_1..S_32, tree arrival -> done broadcast.
// Blocks [NC,NC+NU): stream-unpack S_0..S_32 to float out, gated per layer.
// ---------------------------------------------------------------------------
__global__ __launch_bounds__(256) void coop_kernel(
        const int* __restrict__ src_idx,
        const int* __restrict__ cell_type,
        u32* __restrict__ ws,
        float* __restrict__ out,
        int NU)
{
    u32* Sb = ws + WS_S_OFF;
    int tid = threadIdx.x;
    __shared__ u32 stt[NTYPES];
    if (tid < NTYPES) stt[tid] = ws[tid];
    __syncthreads();

    if ((int)blockIdx.x < NC) {
        // ---------------- compute role ----------------
        int gid = blockIdx.x * 256 + tid;   // word id in [0, WPL)
        int g = gid >> 2, q = gid & 3;
        int sub = blockIdx.x & 63;
        for (int l = 1; l <= LAYERS; ++l) {
            // Index loads issued BEFORE the gate: latency hides under the wait.
            const int4 s = ((const int4*)(src_idx + (size_t)(l - 1) * WGATES * 4))[g];
            u32 ttv = stt[cell_type[(size_t)(l - 1) * WGATES + g]];
            if (l > 1) wait_done(ws, l - 1, sub, tid);
            const u32* Sp = Sb + (size_t)(l - 1) * WPL;
            u32 a = Sp[(u32)s.x * 4 + q];      // normal cached loads
            u32 b = Sp[(u32)s.y * 4 + q];
            u32 c = Sp[(u32)s.z * 4 + q];
            u32 d = Sp[(u32)s.w * 4 + q];
            agent_store(Sb + (size_t)l * WPL + gid, lut_eval(ttv, a, b, c, d));
            asm volatile("s_waitcnt vmcnt(0)" ::: "memory");  // store acked
            __syncthreads();
            if (tid == 0) {
                // Tree arrival: 8 adds/sub-counter, last-arriver promotes.
                u32* subp = ws + WS_SUB_OFF + (size_t)l * 1024 + sub * 16;
                u32 old = agent_add(subp, 1u);
                if (old == (u32)(NC / 64 - 1)) {
                    u32 old2 = agent_add(ws + WS_LVL2_OFF + (size_t)l * 16, 1u);
                    if (old2 == 63u) {
                        u32* donep = ws + WS_DONE_OFF + (size_t)l * 1024;
                        #pragma unroll
                        for (int j = 0; j < 64; ++j)
                            agent_store(donep + j * 16, 1u);
                    }
                }
            }
        }
    } else {
        // ---------------- unpack role ----------------
        int ub = blockIdx.x - NC;
        for (int l = 0; l <= LAYERS; ++l) {
            if (l >= 1) wait_done(ws, l, ub & 63, tid);
            const u32* Sl = Sb + (size_t)l * WPL;
            f4* ob = (f4*)(out + (size_t)l * WGATES * BATCH);
            for (u32 i = (u32)ub * 256u + tid; i < (u32)F4L; i += (u32)NU * 256u) {
                u32 wb = Sl[i >> 3];               // cached (L2-resident)
                u32 sh = (i & 7) * 4;
                f4 f;
                f.x = ((wb >> (sh    )) & 1) ? 1.0f : 0.0f;
                f.y = ((wb >> (sh + 1)) & 1) ? 1.0f : 0.0f;
                f.z = ((wb >> (sh + 2)) & 1) ? 1.0f : 0.0f;
                f.w = ((wb >> (sh + 3)) & 1) ? 1.0f : 0.0f;
                __builtin_nontemporal_store(f, ob + i);   // out never re-read
            }
        }
    }
}

// ======================= R2 fallback path (proven) =========================
__global__ void pack_kernel_fb(const float* __restrict__ feature,
                               const float* __restrict__ activation,
                               float* __restrict__ out,
                               u32* __restrict__ tt_ws,
                               u32* __restrict__ buf0) {
    int t = blockIdx.x * 256 + threadIdx.x;
    if (blockIdx.x == 0 && threadIdx.x < NTYPES) {
        u32 tt = 0;
        #pragma unroll
        for (int m = 0; m < 16; ++m)
            tt |= (activation[threadIdx.x * 16 + m] != 0.0f ? 1u : 0u) << m;
        tt_ws[threadIdx.x] = tt;
    }
    float v = feature[t];
    out[t] = v;
    u64 m = __ballot(v != 0.0f);
    if ((t & 63) == 0)
        ((u64*)buf0)[t >> 6] = m;
}

__global__ void fused_kernel_fb(const u32* __restrict__ prev,
                                u32* __restrict__ next,
                                const int* __restrict__ src_idx,
                                const int* __restrict__ cell_type,
                                const u32* __restrict__ tt_ws,
                                const u32* __restrict__ upacked,
                                float* __restrict__ uout,
                                int do_compute)
{
    int tid = threadIdx.x;
    if (do_compute && blockIdx.x < 512) {
        int gl = tid >> 2, q = tid & 3;
        int wg = blockIdx.x * 64 + gl;
        const int4 s = ((const int4*)src_idx)[wg];
        u32 tt = tt_ws[cell_type[wg]];
        u32 a = prev[(size_t)s.x * 4 + q];
        u32 b = prev[(size_t)s.y * 4 + q];
        u32 c = prev[(size_t)s.z * 4 + q];
        u32 d = prev[(size_t)s.w * 4 + q];
        next[(size_t)wg * 4 + q] = lut_eval(tt, a, b, c, d);
        return;
    }
    if (uout == nullptr) return;
    int ub = do_compute ? (int)blockIdx.x - 512 : (int)blockIdx.x;
    #pragma unroll
    for (int r = 0; r < 2; ++r) {
        int fi = ((ub * 2 + r) * 256 + tid) * 4;
        u32 wb = upacked[fi >> 5];
        int sh = fi & 31;
        f4 f;
        f.x = ((wb >> (sh    )) & 1) ? 1.0f : 0.0f;
        f.y = ((wb >> (sh + 1)) & 1) ? 1.0f : 0.0f;
        f.z = ((wb >> (sh + 2)) & 1) ? 1.0f : 0.0f;
        f.w = ((wb >> (sh + 3)) & 1) ? 1.0f : 0.0f;
        ((f4*)uout)[fi >> 2] = f;
    }
}

static void launch_fallback(const float* feature, const float* activation,
                            const int* src_idx, const int* cell_type,
                            float* out, void* d_ws, hipStream_t stream) {
    u32* tt_ws = (u32*)d_ws;
    u32* bufA = (u32*)((char*)d_ws + 1024);
    u32* bufB = (u32*)((char*)d_ws + 1024 + WGATES * 16);
    pack_kernel_fb<<<WGATES * BATCH / 256, 256, 0, stream>>>(
        feature, activation, out, tt_ws, bufA);
    for (int l = 1; l <= LAYERS; ++l) {
        u32* prev = ((l - 1) & 1) ? bufB : bufA;
        u32* next = ((l - 1) & 1) ? bufA : bufB;
        float* uout = (l >= 2) ? out + (size_t)(l - 1) * WGATES * BATCH : nullptr;
        fused_kernel_fb<<<512 + 2048, 256, 0, stream>>>(
            prev, next,
            src_idx + (size_t)(l - 1) * WGATES * 4,
            cell_type + (size_t)(l - 1) * WGATES,
            tt_ws, prev, uout, 1);
    }
    u32* s32 = ((LAYERS - 1) & 1) ? bufA : bufB;
    fused_kernel_fb<<<2048, 256, 0, stream>>>(
        s32, s32, src_idx, cell_type, tt_ws,
        s32, out + (size_t)LAYERS * WGATES * BATCH, 0);
}

extern "C" void kernel_launch(void* const* d_in, const int* in_sizes, int n_in,
                              void* d_out, int out_size, void* d_ws, size_t ws_size,
                              hipStream_t stream) {
    const float* feature    = (const float*)d_in[0];
    const float* activation = (const float*)d_in[1];
    const int*   src_idx    = (const int*)d_in[2];
    const int*   cell_type  = (const int*)d_in[3];
    float* out = (float*)d_out;

    bool coop_ok = (ws_size >= WS_NEED_BYTES);
    int G = 0, NU = 0;
    if (coop_ok) {
        int dev = 0;
        (void)hipGetDevice(&dev);
        int numCU = 0, bpc = 0;
        if (hipDeviceGetAttribute(&numCU, hipDeviceAttributeMultiprocessorCount, dev)
                != hipSuccess) coop_ok = false;
        if (coop_ok &&
            hipOccupancyMaxActiveBlocksPerMultiprocessor(
                &bpc, (const void*)coop_kernel, 256, 0) != hipSuccess) coop_ok = false;
        if (coop_ok) {
            G = bpc * numCU;
            if (G > 2048) G = 2048;
            NU = G - NC;
            if (NU < 256) coop_ok = false;
        }
    }

    if (coop_ok) {
        u32* ws = (u32*)d_ws;
        pack_main<<<WGATES * BATCH / 256, 256, 0, stream>>>(feature, activation, ws);
        void* args[] = {(void*)&src_idx, (void*)&cell_type, (void*)&ws,
                        (void*)&out, (void*)&NU};
        hipError_t e = hipLaunchCooperativeKernel(
            (const void*)coop_kernel, dim3(G), dim3(256), args, 0, stream);
        if (e == hipSuccess) return;
        // cooperative launch rejected -> fall through
    }
    launch_fallback(feature, activation, src_idx, cell_type, out, d_ws, stream);
}

// Round 8
// 166.552 us; speedup vs baseline: 41.1867x; 1.0101x over previous
//
#include <hip/hip_runtime.h>
#include <stdint.h>

typedef uint32_t u32;
typedef unsigned long long u64;
typedef float f4 __attribute__((ext_vector_type(4)));

#define WGATES 32768
#define BATCH  128
#define LAYERS 32
#define NTYPES 16
#define NC 128                          // compute-role blocks (1 gate/thread)
#define WPL (WGATES * 4)                // packed words per layer = 131072
#define F4L (WGATES * BATCH / 4)        // float4 per layer block = 1048576

// ws layout (u32 units):
//   [0,16)              tt truth tables
//   [1024, 34816)       sub-counters: layer l at 1024+l*1024, j at +j*16
//   [34816, 35344)      lvl2 counters: layer l at 34816+l*16
//   [35840, 69632)      done flags: layer l at 35840+l*1024, j=0..63 at +j*16
//   [69632, +33*WPL)    packed states S_0..S_32 (each address written once)
#define WS_SUB_OFF    1024
#define WS_LVL2_OFF   34816
#define WS_DONE_OFF   35840
#define WS_S_OFF      69632
#define WS_NEED_BYTES ((size_t)(WS_S_OFF + 33 * WPL) * 4)

// Agent-scope (sc1) accesses: ONLY for sync + state release. Data reads use
// normal cached loads (each S_l address is written once; consumers first-touch
// only after the producer's sc1 store reached the coherence point).
__device__ __forceinline__ u32 agent_load(const u32* p) {
    return __hip_atomic_load(p, __ATOMIC_RELAXED, __HIP_MEMORY_SCOPE_AGENT);
}
__device__ __forceinline__ void agent_store(u32* p, u32 v) {
    __hip_atomic_store(p, v, __ATOMIC_RELAXED, __HIP_MEMORY_SCOPE_AGENT);
}
__device__ __forceinline__ void agent_store64(u64* p, u64 v) {
    __hip_atomic_store(p, v, __ATOMIC_RELAXED, __HIP_MEMORY_SCOPE_AGENT);
}
__device__ __forceinline__ u32 agent_add(u32* p, u32 v) {
    return __hip_atomic_fetch_add(p, v, __ATOMIC_RELAXED, __HIP_MEMORY_SCOPE_AGENT);
}

__device__ __forceinline__ void lut_masks(u32 tt, u32 m[16]) {
    #pragma unroll
    for (int j = 0; j < 16; ++j)
        m[j] = (u32)(((int)(tt << (31 - j))) >> 31);
}
__device__ __forceinline__ u32 lut_mux(const u32 m[16], u32 a, u32 b, u32 c, u32 d) {
    u32 na = ~a, nb = ~b, nc = ~c, nd = ~d;
    u32 v0 = (m[1]&a)|(m[0]&na),  v1 = (m[3]&a)|(m[2]&na);
    u32 v2 = (m[5]&a)|(m[4]&na),  v3 = (m[7]&a)|(m[6]&na);
    u32 v4 = (m[9]&a)|(m[8]&na),  v5 = (m[11]&a)|(m[10]&na);
    u32 v6 = (m[13]&a)|(m[12]&na),v7 = (m[15]&a)|(m[14]&na);
    u32 u0 = (b&v1)|(nb&v0), u1 = (b&v3)|(nb&v2);
    u32 u2 = (b&v5)|(nb&v4), u3 = (b&v7)|(nb&v6);
    u32 w0 = (c&u1)|(nc&u0), w1 = (c&u3)|(nc&u2);
    return (d&w1)|(nd&w0);
}

// Single-lane, single-line poll. `slp`: sleep quantum (compute role = 1 for
// fast detect, few pollers; unpack role = 8, off critical path).
__device__ __forceinline__ void wait_done(const u32* ws, int l, int line,
                                          int tid, int slp) {
    if (tid == 0) {
        const u32* p = ws + WS_DONE_OFF + (size_t)l * 1024 + line * 16;
        if (slp == 1) { while (agent_load(p) == 0) __builtin_amdgcn_s_sleep(1); }
        else         { while (agent_load(p) == 0) __builtin_amdgcn_s_sleep(8); }
    }
    __syncthreads();
    asm volatile("" ::: "memory");   // nothing hoisted above the gate
}

// ---------------------------------------------------------------------------
// pack_main: tt tables -> ws, zero all sync state, pack h0 -> S_0.
// ---------------------------------------------------------------------------
__global__ void pack_main(const float* __restrict__ feature,
                          const float* __restrict__ activation,
                          u32* __restrict__ ws) {
    int t = blockIdx.x * 256 + threadIdx.x;
    if (blockIdx.x == 0 && threadIdx.x < NTYPES) {
        u32 tt = 0;
        #pragma unroll
        for (int m = 0; m < 16; ++m)
            tt |= (activation[threadIdx.x * 16 + m] != 0.0f ? 1u : 0u) << m;
        ws[threadIdx.x] = tt;
    }
    int z = (int)blockIdx.x - 1;
    if (z >= 0 && z < 268)             // zero [1024, 69632): sub+lvl2+done
        ws[1024 + z * 256 + threadIdx.x] = 0;
    float v = feature[t];
    u64 m = __ballot(v != 0.0f);
    if ((t & 63) == 0)
        ((u64*)(ws + WS_S_OFF))[t >> 6] = m;
}

// ---------------------------------------------------------------------------
// Persistent producer-consumer kernel (cooperative launch for residency).
// Blocks [0,NC): compute chain, ONE GATE PER THREAD (dwordx4 gathers, all 4
//   batch-words per thread, masks computed once), tree arrival -> done bcast.
// Blocks [NC,NC+NU): stream-unpack S_0..S_32 to float out, XCD-affine slices.
// ---------------------------------------------------------------------------
__global__ __launch_bounds__(256) void coop_kernel(
        const int* __restrict__ src_idx,
        const int* __restrict__ cell_type,
        u32* __restrict__ ws,
        float* __restrict__ out,
        int NU)
{
    u32* Sb = ws + WS_S_OFF;
    int tid = threadIdx.x;
    __shared__ u32 stt[NTYPES];
    if (tid < NTYPES) stt[tid] = ws[tid];
    __syncthreads();

    if ((int)blockIdx.x < NC) {
        // ---------------- compute role: gate-per-thread ----------------
        int g = blockIdx.x * 256 + tid;     // gate id in [0, WGATES)
        int sub = blockIdx.x & 15;          // 16 sub-counters x 8 blocks
        for (int l = 1; l <= LAYERS; ++l) {
            // Index loads issued BEFORE the gate: latency hides under the wait.
            const int4 s = ((const int4*)(src_idx + (size_t)(l - 1) * WGATES * 4))[g];
            u32 ttv = stt[cell_type[(size_t)(l - 1) * WGATES + g]];
            if (l > 1) wait_done(ws, l - 1, sub, tid, 1);
            const uint4* Sp = (const uint4*)(Sb + (size_t)(l - 1) * WPL);
            uint4 A = Sp[(u32)s.x];          // normal cached dwordx4 loads
            uint4 B = Sp[(u32)s.y];
            uint4 C = Sp[(u32)s.z];
            uint4 D = Sp[(u32)s.w];
            u32 m[16];
            lut_masks(ttv, m);
            u32 r0 = lut_mux(m, A.x, B.x, C.x, D.x);
            u32 r1 = lut_mux(m, A.y, B.y, C.y, D.y);
            u32 r2 = lut_mux(m, A.z, B.z, C.z, D.z);
            u32 r3 = lut_mux(m, A.w, B.w, C.w, D.w);
            u64* dst = (u64*)(Sb + (size_t)l * WPL + (size_t)g * 4);
            agent_store64(dst,     ((u64)r1 << 32) | r0);   // sc1 release
            agent_store64(dst + 1, ((u64)r3 << 32) | r2);
            asm volatile("s_waitcnt vmcnt(0)" ::: "memory");  // stores acked
            __syncthreads();
            if (tid == 0) {
                u32* subp = ws + WS_SUB_OFF + (size_t)l * 1024 + sub * 16;
                u32 old = agent_add(subp, 1u);
                if (old == (u32)(NC / 16 - 1)) {
                    u32 old2 = agent_add(ws + WS_LVL2_OFF + (size_t)l * 16, 1u);
                    if (old2 == 15u) {
                        u32* donep = ws + WS_DONE_OFF + (size_t)l * 1024;
                        #pragma unroll
                        for (int j = 0; j < 64; ++j)
                            agent_store(donep + j * 16, 1u);
                    }
                }
            }
        }
    } else {
        // ---------------- unpack role ----------------
        int ub = blockIdx.x - NC;
        bool sliced = (NU & 7) == 0;        // XCD-affine slicing (NC%8==0)
        int x = ub & 7;                     // presumed XCD (blockIdx % 8)
        u32 per = (u32)(NU >> 3);           // blocks per slice
        for (int l = 0; l <= LAYERS; ++l) {
            if (l >= 1) wait_done(ws, l, ub & 63, tid, 8);
            const u32* Sl = Sb + (size_t)l * WPL;
            f4* ob = (f4*)(out + (size_t)l * WGATES * BATCH);
            if (sliced) {
                u32 sbeg = (u32)x * (F4L / 8), send = sbeg + F4L / 8;
                for (u32 i = sbeg + (u32)(ub >> 3) * 256u + tid; i < send;
                     i += per * 256u) {
                    u32 wb = Sl[i >> 3];
                    u32 sh = (i & 7) * 4;
                    f4 f;
                    f.x = ((wb >> (sh    )) & 1) ? 1.0f : 0.0f;
                    f.y = ((wb >> (sh + 1)) & 1) ? 1.0f : 0.0f;
                    f.z = ((wb >> (sh + 2)) & 1) ? 1.0f : 0.0f;
                    f.w = ((wb >> (sh + 3)) & 1) ? 1.0f : 0.0f;
                    __builtin_nontemporal_store(f, ob + i);
                }
            } else {
                for (u32 i = (u32)ub * 256u + tid; i < (u32)F4L;
                     i += (u32)NU * 256u) {
                    u32 wb = Sl[i >> 3];
                    u32 sh = (i & 7) * 4;
                    f4 f;
                    f.x = ((wb >> (sh    )) & 1) ? 1.0f : 0.0f;
                    f.y = ((wb >> (sh + 1)) & 1) ? 1.0f : 0.0f;
                    f.z = ((wb >> (sh + 2)) & 1) ? 1.0f : 0.0f;
                    f.w = ((wb >> (sh + 3)) & 1) ? 1.0f : 0.0f;
                    __builtin_nontemporal_store(f, ob + i);
                }
            }
        }
    }
}

// ======================= R2 fallback path (proven) =========================
__global__ void pack_kernel_fb(const float* __restrict__ feature,
                               const float* __restrict__ activation,
                               float* __restrict__ out,
                               u32* __restrict__ tt_ws,
                               u32* __restrict__ buf0) {
    int t = blockIdx.x * 256 + threadIdx.x;
    if (blockIdx.x == 0 && threadIdx.x < NTYPES) {
        u32 tt = 0;
        #pragma unroll
        for (int m = 0; m < 16; ++m)
            tt |= (activation[threadIdx.x * 16 + m] != 0.0f ? 1u : 0u) << m;
        tt_ws[threadIdx.x] = tt;
    }
    float v = feature[t];
    out[t] = v;
    u64 m = __ballot(v != 0.0f);
    if ((t & 63) == 0)
        ((u64*)buf0)[t >> 6] = m;
}

__global__ void fused_kernel_fb(const u32* __restrict__ prev,
                                u32* __restrict__ next,
                                const int* __restrict__ src_idx,
                                const int* __restrict__ cell_type,
                                const u32* __restrict__ tt_ws,
                                const u32* __restrict__ upacked,
                                float* __restrict__ uout,
                                int do_compute)
{
    int tid = threadIdx.x;
    if (do_compute && blockIdx.x < 512) {
        int gl = tid >> 2, q = tid & 3;
        int wg = blockIdx.x * 64 + gl;
        const int4 s = ((const int4*)src_idx)[wg];
        u32 tt = tt_ws[cell_type[wg]];
        u32 m[16];
        lut_masks(tt, m);
        u32 a = prev[(size_t)s.x * 4 + q];
        u32 b = prev[(size_t)s.y * 4 + q];
        u32 c = prev[(size_t)s.z * 4 + q];
        u32 d = prev[(size_t)s.w * 4 + q];
        next[(size_t)wg * 4 + q] = lut_mux(m, a, b, c, d);
        return;
    }
    if (uout == nullptr) return;
    int ub = do_compute ? (int)blockIdx.x - 512 : (int)blockIdx.x;
    #pragma unroll
    for (int r = 0; r < 2; ++r) {
        int fi = ((ub * 2 + r) * 256 + tid) * 4;
        u32 wb = upacked[fi >> 5];
        int sh = fi & 31;
        f4 f;
        f.x = ((wb >> (sh    )) & 1) ? 1.0f : 0.0f;
        f.y = ((wb >> (sh + 1)) & 1) ? 1.0f : 0.0f;
        f.z = ((wb >> (sh + 2)) & 1) ? 1.0f : 0.0f;
        f.w = ((wb >> (sh + 3)) & 1) ? 1.0f : 0.0f;
        ((f4*)uout)[fi >> 2] = f;
    }
}

static void launch_fallback(const float* feature, const float* activation,
                            const int* src_idx, const int* cell_type,
                            float* out, void* d_ws, hipStream_t stream) {
    u32* tt_ws = (u32*)d_ws;
    u32* bufA = (u32*)((char*)d_ws + 1024);
    u32* bufB = (u32*)((char*)d_ws + 1024 + WGATES * 16);
    pack_kernel_fb<<<WGATES * BATCH / 256, 256, 0, stream>>>(
        feature, activation, out, tt_ws, bufA);
    for (int l = 1; l <= LAYERS; ++l) {
        u32* prev = ((l - 1) & 1) ? bufB : bufA;
        u32* next = ((l - 1) & 1) ? bufA : bufB;
        float* uout = (l >= 2) ? out + (size_t)(l - 1) * WGATES * BATCH : nullptr;
        fused_kernel_fb<<<512 + 2048, 256, 0, stream>>>(
            prev, next,
            src_idx + (size_t)(l - 1) * WGATES * 4,
            cell_type + (size_t)(l - 1) * WGATES,
            tt_ws, prev, uout, 1);
    }
    u32* s32 = ((LAYERS - 1) & 1) ? bufA : bufB;
    fused_kernel_fb<<<2048, 256, 0, stream>>>(
        s32, s32, src_idx, cell_type, tt_ws,
        s32, out + (size_t)LAYERS * WGATES * BATCH, 0);
}

extern "C" void kernel_launch(void* const* d_in, const int* in_sizes, int n_in,
                              void* d_out, int out_size, void* d_ws, size_t ws_size,
                              hipStream_t stream) {
    const float* feature    = (const float*)d_in[0];
    const float* activation = (const float*)d_in[1];
    const int*   src_idx    = (const int*)d_in[2];
    const int*   cell_type  = (const int*)d_in[3];
    float* out = (float*)d_out;

    bool coop_ok = (ws_size >= WS_NEED_BYTES);
    int G = 0, NU = 0;
    if (coop_ok) {
        int dev = 0;
        (void)hipGetDevice(&dev);
        int numCU = 0, bpc = 0;
        if (hipDeviceGetAttribute(&numCU, hipDeviceAttributeMultiprocessorCount, dev)
                != hipSuccess) coop_ok = false;
        if (coop_ok &&
            hipOccupancyMaxActiveBlocksPerMultiprocessor(
                &bpc, (const void*)coop_kernel, 256, 0) != hipSuccess) coop_ok = false;
        if (coop_ok) {
            G = bpc * numCU;
            if (G > 2048) G = 2048;
            NU = G - NC;
            if (NU < 256) coop_ok = false;
        }
    }

    if (coop_ok) {
        u32* ws = (u32*)d_ws;
        pack_main<<<WGATES * BATCH / 256, 256, 0, stream>>>(feature, activation, ws);
        void* args[] = {(void*)&src_idx, (void*)&cell_type, (void*)&ws,
                        (void*)&out, (void*)&NU};
        hipError_t e = hipLaunchCooperativeKernel(
            (const void*)coop_kernel, dim3(G), dim3(256), args, 0, stream);
        if (e == hipSuccess) return;
        // cooperative launch rejected -> fall through
    }
    launch_fallback(feature, activation, src_idx, cell_type, out, d_ws, stream);
}